// Round 6
// baseline (167.000 us; speedup 1.0000x reference)
//
#include <hip/hip_runtime.h>
#include <cstddef>

#define S_ 2048
#define E_ 512
#define SPLIT_STRIDE 4194304u   // ushort elements per AO partial (4*2048*512)

typedef __attribute__((ext_vector_type(8)))  short bf16x8;
typedef __attribute__((ext_vector_type(16))) float f32x16;

__device__ __forceinline__ unsigned short f2bf(float f) {
    union { float f; unsigned u; } v; v.f = f;
    return (unsigned short)((v.u + 0x7FFFu + ((v.u >> 16) & 1u)) >> 16);
}
// pack two floats to bf16x2 (round-half-up): low16 = bf16(a), high16 = bf16(b)
__device__ __forceinline__ unsigned pk2bf(float a, float b) {
    union { float f; unsigned u; } x, y; x.f = a; y.f = b;
    return __builtin_amdgcn_perm(y.u + 0x8000u, x.u + 0x8000u, 0x07060302u);
}
__device__ __forceinline__ float bflo(unsigned u) {
    union { unsigned u; float f; } v; v.u = u << 16; return v.f;
}
__device__ __forceinline__ float bfhi(unsigned u) {
    union { unsigned u; float f; } v; v.u = u & 0xffff0000u; return v.f;
}
// guaranteed-bare v_exp_f32: scores are bounded, no OCML guards needed
__device__ __forceinline__ float fexp2(float x) {
    float r;
    asm("v_exp_f32 %0, %1" : "=v"(r) : "v"(x));
    return r;
}

// ---------------- fused prep: X conversion/transpose + GT + W2 ----------------
// Round-6: the 64x64 transpose used 16 scalar ds_write_u16 + 16 scalar
// ds_read_u16 per thread (32 scalar LDS ops, bank-aliased). Replaced with
// uint-pair staging: 2x ds_write_b128 + 16x ds_read_b32 (+8 v_perm splices).
// Layout addr(s,d2) = (s>>4)*580 + (s&15)*36 + d2 (uints): rows 16B-aligned,
// read banks = 4g + 4*pm + d2 mod 32 -> worst 2-way (free, m136).
__global__ __launch_bounds__(256) void prep_all(const float* __restrict__ X,
                                                const float* __restrict__ Wq,
                                                const float* __restrict__ Wk,
                                                const float* __restrict__ Wo,
                                                const float* __restrict__ Wv,
                                                unsigned short* __restrict__ Xbf,
                                                unsigned short* __restrict__ XTg,
                                                unsigned short* __restrict__ GT,
                                                unsigned short* __restrict__ W2) {
    __shared__ unsigned Tt[2320];          // 9,280 B
    const int bi = blockIdx.x, tid = threadIdx.x;
    if (bi < 1024) {
        const int st = bi & 31, h = (bi >> 5) & 7, b = bi >> 8;
        const int s0 = st * 64;
        const int j = tid >> 2, g = tid & 3;
        const float* src = X + ((size_t)(b * S_ + s0 + j) * E_) + h * 64 + g * 16;
        unsigned short us[16];
#pragma unroll
        for (int i = 0; i < 16; i += 4) {
            float4 f = *(const float4*)(src + i);
            us[i] = f2bf(f.x); us[i + 1] = f2bf(f.y);
            us[i + 2] = f2bf(f.z); us[i + 3] = f2bf(f.w);
        }
        size_t xb = ((size_t)(b * S_ + s0 + j) * E_) + h * 64 + g * 16;
        *(uint4*)&Xbf[xb]     = *(uint4*)&us[0];
        *(uint4*)&Xbf[xb + 8] = *(uint4*)&us[8];
        // stage as d-pairs: Tt[addr(j, g*8+k)] = (bf16 d=2k', d=2k'+1) of X row j
        {
            const unsigned* p = (const unsigned*)us;   // p[k] = us[2k] | us[2k+1]<<16
            const int base = (j >> 4) * 580 + (j & 15) * 36 + g * 8;
            *(uint4*)&Tt[base]     = *(const uint4*)&p[0];
            *(uint4*)&Tt[base + 4] = *(const uint4*)&p[4];
        }
        __syncthreads();
        // read back transposed+permuted: out[i] = X[s0 + g*16 + pm[i]][d]
        const int d = tid >> 2;
        const int pm[16] = {0,1,2,3,8,9,10,11,4,5,6,7,12,13,14,15};
        const unsigned sel = (d & 1) ? 0x07060302u : 0x05040100u;
        const int rb = g * 580;            // row-group base (rows g*16 + r -> sg = g)
        const int d2 = d >> 1;
        unsigned o32[8];
#pragma unroll
        for (int k = 0; k < 8; ++k) {
            unsigned va = Tt[rb + pm[2 * k]     * 36 + d2];
            unsigned vb = Tt[rb + (pm[2 * k] + 1) * 36 + d2];   // pm pairs are +1-adjacent
            o32[k] = __builtin_amdgcn_perm(vb, va, sel);
        }
        size_t tb = ((size_t)((b * 8 + h) * 64 + d)) * S_ + s0 + g * 16;
        *(uint4*)&XTg[tb]     = *(const uint4*)&o32[0];
        *(uint4*)&XTg[tb + 8] = *(const uint4*)&o32[4];
    } else if (bi < 1040) {
        int idx = (bi - 1024) * 256 + tid;
        int c = idx >> 6, d = idx & 63;
        float acc = 0.f;
#pragma unroll 8
        for (int e = 0; e < 64; ++e) acc += Wq[e * 64 + d] * Wk[e * 64 + c];
        GT[c * 64 + d] = f2bf(acc * 0.18033688011112042f);   // log2(e)/sqrt(64)
    } else {
        int idx = (bi - 1040) * 256 + tid;
        int e = idx >> 9, f = idx & 511;
        int h = f >> 6, c = f & 63;
        const float* wo = Wo + e * 512 + h * 64;
        float acc = 0.f;
#pragma unroll 8
        for (int d = 0; d < 64; ++d) acc += wo[d] * Wv[d * 64 + c];
        W2[idx] = f2bf(acc);
    }
}

// ---------------- MFMA flash attention, K-split=2, double-buffered ----------------
// Round-4 version verbatim (passing, 49.8 us): 1024 blocks x 128 threads;
// blk&7 = h -> one head per XCD; 2 waves, 64 q/wave as two 32-q B-groups.
__global__ __launch_bounds__(128, 2) void attn_mfma(const unsigned short* __restrict__ Xbf,
                                                    const unsigned short* __restrict__ XTg,
                                                    const unsigned short* __restrict__ GT,
                                                    unsigned short* __restrict__ AOp,
                                                    float* __restrict__ Lp) {
    __shared__ union SM {
        unsigned short Q[128][72];          // startup Q/U staging (18,432 B)
        unsigned char  cb[2][2][8192];      // [buf][Xrm|XT][64 rows x 128 B] (32,768 B)
        unsigned short AOt[128][72];        // epilogue bounce
    } sm;

    const int tid = threadIdx.x;
    const int w = tid >> 6, lane = tid & 63;
    const int lm = lane & 31, lh = lane >> 5;
    const int h = blockIdx.x & 7;
    const int rest = blockIdx.x >> 3;            // 0..127
    const int qt = rest & 15, b = (rest >> 4) & 3, split = rest >> 6;
    const int s0 = qt * 128, sk0 = split * (S_ / 2);

    // ---- stage 128 Q rows (2 passes of 64 rows with 128 threads)
    {
        const int r = tid >> 1, c = (tid & 1) * 32;
#pragma unroll
        for (int p = 0; p < 2; ++p) {
            const unsigned short* src = Xbf + ((size_t)(b * S_ + s0 + 64 * p + r)) * E_ + h * 64 + c;
#pragma unroll
            for (int u = 0; u < 4; ++u)
                *(uint4*)&sm.Q[64 * p + r][c + u * 8] = *(const uint4*)(src + u * 8);
        }
    }
    __syncthreads();

    // ---- U = Xq @ (G*kScale), 64 queries per wave; LDS round-trip within own
    // wave's rows; keep B-frags for both q-groups in regs (verified math)
    bf16x8 Ufrag[2][4];
    {
        f32x16 ua[2][2];
#pragma unroll
        for (int mt = 0; mt < 2; ++mt)
#pragma unroll
            for (int nt = 0; nt < 2; ++nt)
#pragma unroll
                for (int i = 0; i < 16; ++i) ua[mt][nt][i] = 0.f;
#pragma unroll
        for (int ks = 0; ks < 4; ++ks) {
            bf16x8 bG0 = *(const bf16x8*)&GT[(lm +  0) * 64 + ks * 16 + lh * 8];
            bf16x8 bG1 = *(const bf16x8*)&GT[(lm + 32) * 64 + ks * 16 + lh * 8];
#pragma unroll
            for (int mt = 0; mt < 2; ++mt) {
                bf16x8 aQ = *(const bf16x8*)&sm.Q[64 * w + 32 * mt + lm][ks * 16 + lh * 8];
                ua[mt][0] = __builtin_amdgcn_mfma_f32_32x32x16_bf16(aQ, bG0, ua[mt][0], 0, 0, 0);
                ua[mt][1] = __builtin_amdgcn_mfma_f32_32x32x16_bf16(aQ, bG1, ua[mt][1], 0, 0, 0);
            }
        }
#pragma unroll
        for (int mt = 0; mt < 2; ++mt)
#pragma unroll
            for (int nt = 0; nt < 2; ++nt)
#pragma unroll
                for (int r = 0; r < 16; ++r)
                    sm.Q[64 * w + 32 * mt + (r & 3) + 8 * (r >> 2) + 4 * lh][lm + 32 * nt] =
                        f2bf(ua[mt][nt][r]);
#pragma unroll
        for (int g = 0; g < 2; ++g)
#pragma unroll
            for (int ks = 0; ks < 4; ++ks)
                Ufrag[g][ks] = *(const bf16x8*)&sm.Q[64 * w + 32 * g + lm][ks * 16 + lh * 8];
    }
    __syncthreads();   // all U-phase LDS traffic done before cb staging clobbers union

    // ---- pre-swizzled per-lane global source addresses for gload_lds staging.
    const int il = lane >> 3;                         // sub-row within one 1 KiB instr
    const int swc = ((lane & 7) ^ (il & 7)) * 8;      // swizzled col, ushort units
    const unsigned short* gX0 = Xbf + ((size_t)(b * S_ + sk0 + 32 * w + il)) * E_ + h * 64 + swc;
    const unsigned short* gT0 = XTg + ((size_t)((b * 8 + h) * 64 + 32 * w + il)) * S_ + sk0 + swc;

    // stage chunk 0 into cb[0]
#pragma unroll
    for (int i8 = 0; i8 < 4; ++i8) {
        __builtin_amdgcn_global_load_lds((const unsigned*)(gX0 + (size_t)i8 * 8 * E_),
                                         (unsigned*)&sm.cb[0][0][(4 * w + i8) * 1024], 16, 0, 0);
        __builtin_amdgcn_global_load_lds((const unsigned*)(gT0 + (size_t)i8 * 8 * S_),
                                         (unsigned*)&sm.cb[0][1][(4 * w + i8) * 1024], 16, 0, 0);
    }
    __syncthreads();

    float lsum0 = 0.f, lsum1 = 0.f;
    f32x16 AO[2][2];
#pragma unroll
    for (int mt = 0; mt < 2; ++mt)
#pragma unroll
        for (int nt = 0; nt < 2; ++nt)
#pragma unroll
            for (int i = 0; i < 16; ++i) AO[mt][nt][i] = 0.f;

    // shared const-zero accumulator seed: C operand of every chunk's ks=0 MFMAs
    f32x16 zv;
#pragma unroll
    for (int i = 0; i < 16; ++i) zv[i] = 0.f;

    const int xorr = (lm & 7) << 4;                   // read-side swizzle term

    for (int ck = 0; ck < 16; ++ck) {
        const int rb = ck & 1;
        // issue next-chunk staging FIRST: loads fly across the whole compute phase
        if (ck < 15) {
            const unsigned short* sX = gX0 + (size_t)(ck + 1) * 64 * E_;
            const unsigned short* sT = gT0 + (ck + 1) * 64;
            unsigned char* dX = &sm.cb[rb ^ 1][0][4 * w * 1024];
            unsigned char* dT = &sm.cb[rb ^ 1][1][4 * w * 1024];
#pragma unroll
            for (int i8 = 0; i8 < 4; ++i8) {
                __builtin_amdgcn_global_load_lds((const unsigned*)(sX + (size_t)i8 * 8 * E_),
                                                 (unsigned*)(dX + i8 * 1024), 16, 0, 0);
                __builtin_amdgcn_global_load_lds((const unsigned*)(sT + (size_t)i8 * 8 * S_),
                                                 (unsigned*)(dT + i8 * 1024), 16, 0, 0);
            }
        }

        const unsigned char* bX = sm.cb[rb][0];
        const unsigned char* bT = sm.cb[rb][1];

        // ---- QK: ALL 64 scores as one MFMA cluster; ks=0 seeds from const zv
        f32x16 sc[2][2];
        __builtin_amdgcn_s_setprio(1);
#pragma unroll
        for (int mt = 0; mt < 2; ++mt) {
            bf16x8 aX = *(const bf16x8*)(bX + (32 * mt + lm) * 128 + ((lh * 16) ^ xorr));
            sc[mt][0] = __builtin_amdgcn_mfma_f32_32x32x16_bf16(aX, Ufrag[0][0], zv, 0, 0, 0);
            sc[mt][1] = __builtin_amdgcn_mfma_f32_32x32x16_bf16(aX, Ufrag[1][0], zv, 0, 0, 0);
        }
#pragma unroll
        for (int ks = 1; ks < 4; ++ks)
#pragma unroll
            for (int mt = 0; mt < 2; ++mt) {
                bf16x8 aX = *(const bf16x8*)(bX + (32 * mt + lm) * 128 + ((ks * 32 + lh * 16) ^ xorr));
                sc[mt][0] = __builtin_amdgcn_mfma_f32_32x32x16_bf16(aX, Ufrag[0][ks], sc[mt][0], 0, 0, 0);
                sc[mt][1] = __builtin_amdgcn_mfma_f32_32x32x16_bf16(aX, Ufrag[1][ks], sc[mt][1], 0, 0, 0);
            }
        __builtin_amdgcn_s_setprio(0);

        // ---- exp/PV streamed per-js: exp(js) overlaps QK tail / PV(js-1)
#pragma unroll
        for (int js = 0; js < 4; ++js) {
            const int mt = js >> 1, jh = js & 1;
            union { unsigned u[4]; bf16x8 v; } bP0, bP1;
#pragma unroll
            for (int i = 0; i < 4; ++i) {
                const int qq = 2 * jh + (i >> 1);
                float pa = fexp2(sc[mt][0][qq * 4 + 2 * (i & 1)]);
                float pb = fexp2(sc[mt][0][qq * 4 + 2 * (i & 1) + 1]);
                lsum0 += pa + pb;
                bP0.u[i] = pk2bf(pa, pb);
                float pc = fexp2(sc[mt][1][qq * 4 + 2 * (i & 1)]);
                float pd = fexp2(sc[mt][1][qq * 4 + 2 * (i & 1) + 1]);
                lsum1 += pc + pd;
                bP1.u[i] = pk2bf(pc, pd);
            }
            __builtin_amdgcn_s_setprio(1);
#pragma unroll
            for (int mtv = 0; mtv < 2; ++mtv) {
                bf16x8 aT = *(const bf16x8*)(bT + (32 * mtv + lm) * 128 + ((js * 32 + lh * 16) ^ xorr));
                AO[mtv][0] = __builtin_amdgcn_mfma_f32_32x32x16_bf16(aT, bP0.v, AO[mtv][0], 0, 0, 0);
                AO[mtv][1] = __builtin_amdgcn_mfma_f32_32x32x16_bf16(aT, bP1.v, AO[mtv][1], 0, 0, 0);
            }
            __builtin_amdgcn_s_setprio(0);
        }
        // one barrier per chunk: drains gload_lds (vmcnt) + all LDS reads, then swap
        __syncthreads();
    }

    // ---- epilogue: combine lane halves of lsum; write UNNORMALIZED bf16 partial
    lsum0 += __shfl_xor(lsum0, 32);
    lsum1 += __shfl_xor(lsum1, 32);
#pragma unroll
    for (int mtv = 0; mtv < 2; ++mtv)
#pragma unroll
        for (int nt = 0; nt < 2; ++nt)
#pragma unroll
            for (int qq = 0; qq < 4; ++qq) {
                const int d0 = 32 * mtv + 8 * qq + 4 * lh;
                const int row = 64 * w + 32 * nt + lm;
                *(unsigned*)&sm.AOt[row][d0] =
                    pk2bf(AO[mtv][nt][qq * 4 + 0], AO[mtv][nt][qq * 4 + 1]);
                *(unsigned*)&sm.AOt[row][d0 + 2] =
                    pk2bf(AO[mtv][nt][qq * 4 + 2], AO[mtv][nt][qq * 4 + 3]);
            }
    __syncthreads();
    {
        const int r = tid >> 1, c = (tid & 1) * 32;
#pragma unroll
        for (int p = 0; p < 2; ++p) {
            unsigned short* dst = AOp + (size_t)split * SPLIT_STRIDE
                                + ((size_t)(b * S_ + s0 + 64 * p + r)) * E_ + h * 64 + c;
#pragma unroll
            for (int u = 0; u < 4; ++u)
                *(uint4*)(dst + u * 8) = *(const uint4*)&sm.AOt[64 * p + r][c + u * 8];
        }
    }
    if (lane < 32) {
        const size_t lb = ((size_t)(split * 4 + b) * 8 + h) * S_ + s0 + 64 * w;
        Lp[lb + lm]      = lsum0;
        Lp[lb + 32 + lm] = lsum1;
    }
}

// ---------------- output GEMM with fused split-combine + normalize ----------------
__global__ __launch_bounds__(256) void out_gemm_bf(const unsigned short* __restrict__ AOp,
                                                   const float* __restrict__ Lp,
                                                   const unsigned short* __restrict__ W2,
                                                   const float* __restrict__ bo,
                                                   float* __restrict__ out) {
    __shared__ unsigned short At[64][72];
    __shared__ unsigned short Bt[64][72];
    const int tid = threadIdx.x;
    const int w = tid >> 6, lane = tid & 63;
    const int lm = lane & 31, lh = lane >> 5;
    const int et = blockIdx.x & 7, rt = blockIdx.x >> 3;
    const int r0 = rt * 64, e0 = et * 64;
    const int rr = tid >> 2, cc = (tid & 3) * 16;
    const int srow = r0 + rr, bb = srow >> 11, ss = srow & 2047;

    f32x16 acc;
#pragma unroll
    for (int i = 0; i < 16; ++i) acc[i] = 0.f;

    for (int k0 = 0; k0 < 512; k0 += 64) {
        const int hh = k0 >> 6;
        const float linv = 1.0f / (Lp[((size_t)(bb)*8 + hh) * S_ + ss] +
                                   Lp[((size_t)(4 + bb) * 8 + hh) * S_ + ss]);
        __syncthreads();
        {
            const unsigned short* a0 = AOp + (size_t)srow * 512 + k0 + cc;
            const unsigned short* a1 = a0 + SPLIT_STRIDE;
            uint4 u0 = *(const uint4*)a0, u0b = *(const uint4*)(a0 + 8);
            uint4 u1 = *(const uint4*)a1, u1b = *(const uint4*)(a1 + 8);
            uint4 o, ob;
            o.x  = pk2bf((bflo(u0.x) + bflo(u1.x)) * linv, (bfhi(u0.x) + bfhi(u1.x)) * linv);
            o.y  = pk2bf((bflo(u0.y) + bflo(u1.y)) * linv, (bfhi(u0.y) + bfhi(u1.y)) * linv);
            o.z  = pk2bf((bflo(u0.z) + bflo(u1.z)) * linv, (bfhi(u0.z) + bfhi(u1.z)) * linv);
            o.w  = pk2bf((bflo(u0.w) + bflo(u1.w)) * linv, (bfhi(u0.w) + bfhi(u1.w)) * linv);
            ob.x = pk2bf((bflo(u0b.x) + bflo(u1b.x)) * linv, (bfhi(u0b.x) + bfhi(u1b.x)) * linv);
            ob.y = pk2bf((bflo(u0b.y) + bflo(u1b.y)) * linv, (bfhi(u0b.y) + bfhi(u1b.y)) * linv);
            ob.z = pk2bf((bflo(u0b.z) + bflo(u1b.z)) * linv, (bfhi(u0b.z) + bfhi(u1b.z)) * linv);
            ob.w = pk2bf((bflo(u0b.w) + bflo(u1b.w)) * linv, (bfhi(u0b.w) + bfhi(u1b.w)) * linv);
            *(uint4*)&At[rr][cc]     = o;
            *(uint4*)&At[rr][cc + 8] = ob;
            const unsigned short* sb = W2 + (size_t)(e0 + rr) * 512 + k0 + cc;
            *(uint4*)&Bt[rr][cc]     = *(const uint4*)sb;
            *(uint4*)&Bt[rr][cc + 8] = *(const uint4*)(sb + 8);
        }
        __syncthreads();
#pragma unroll
        for (int ks = 0; ks < 4; ++ks) {
            bf16x8 aA = *(const bf16x8*)&At[32 * (w & 1) + lm][ks * 16 + lh * 8];
            bf16x8 bW = *(const bf16x8*)&Bt[32 * (w >> 1) + lm][ks * 16 + lh * 8];
            acc = __builtin_amdgcn_mfma_f32_32x32x16_bf16(aA, bW, acc, 0, 0, 0);
        }
    }
    const float bv = bo[e0 + 32 * (w >> 1) + lm];
#pragma unroll
    for (int r = 0; r < 16; ++r) {
        int orow = r0 + 32 * (w & 1) + (r & 3) + 8 * (r >> 2) + 4 * lh;
        out[(size_t)orow * 512 + e0 + 32 * (w >> 1) + lm] = acc[r] + bv;
    }
}

extern "C" void kernel_launch(void* const* d_in, const int* in_sizes, int n_in,
                              void* d_out, int out_size, void* d_ws, size_t ws_size,
                              hipStream_t stream) {
    (void)in_sizes; (void)n_in; (void)out_size; (void)ws_size;
    const float* X  = (const float*)d_in[0];   // queries (K/V derive from it, per reference)
    const float* Wq = (const float*)d_in[3];
    const float* Wk = (const float*)d_in[4];
    const float* Wv = (const float*)d_in[5];
    const float* Wo = (const float*)d_in[6];
    const float* bo = (const float*)d_in[7];

    float* ws = (float*)d_ws;
    unsigned short* W2bf = (unsigned short*)ws;                        // 262,144 us
    unsigned short* GT   = (unsigned short*)(ws + 131072);             // 4,096 us
    unsigned short* Xbf  = (unsigned short*)(ws + 133120);             // 4,194,304 us
    unsigned short* XTg  = (unsigned short*)(ws + 2230272);            // 4,194,304 us
    unsigned short* AOp  = (unsigned short*)(ws + 4327424);            // 2 x 4,194,304 us
    float*          Lp   = ws + 8521728;                               // 131,072 f (~34.6 MB total)

    prep_all   <<<2064, 256, 0, stream>>>(X, Wq, Wk, Wo, Wv, Xbf, XTg, GT, W2bf);
    attn_mfma  <<<1024, 128, 0, stream>>>(Xbf, XTg, GT, AOp, Lp);
    out_gemm_bf<<<1024, 256, 0, stream>>>(AOp, Lp, W2bf, bo, (float*)d_out);
}

// Round 7
// 161.121 us; speedup vs baseline: 1.0365x; 1.0365x over previous
//
#include <hip/hip_runtime.h>
#include <cstddef>

#define S_ 2048
#define E_ 512
#define SPLIT_STRIDE 4194304u   // ushort elements per AO partial (4*2048*512)

typedef __attribute__((ext_vector_type(8)))  short bf16x8;
typedef __attribute__((ext_vector_type(16))) float f32x16;

__device__ __forceinline__ unsigned short f2bf(float f) {
    union { float f; unsigned u; } v; v.f = f;
    return (unsigned short)((v.u + 0x7FFFu + ((v.u >> 16) & 1u)) >> 16);
}
// pack two floats to bf16x2 (round-half-up): low16 = bf16(a), high16 = bf16(b)
__device__ __forceinline__ unsigned pk2bf(float a, float b) {
    union { float f; unsigned u; } x, y; x.f = a; y.f = b;
    return __builtin_amdgcn_perm(y.u + 0x8000u, x.u + 0x8000u, 0x07060302u);
}
__device__ __forceinline__ float bflo(unsigned u) {
    union { unsigned u; float f; } v; v.u = u << 16; return v.f;
}
__device__ __forceinline__ float bfhi(unsigned u) {
    union { unsigned u; float f; } v; v.u = u & 0xffff0000u; return v.f;
}
// guaranteed-bare v_exp_f32: scores are bounded, no OCML guards needed
__device__ __forceinline__ float fexp2(float x) {
    float r;
    asm("v_exp_f32 %0, %1" : "=v"(r) : "v"(x));
    return r;
}

// ---------------- fused prep: X conversion/transpose + GT + W2 ----------------
// (r6 version: uint-pair LDS staging, 2x b128 write + 16x b32 read + v_perm)
__global__ __launch_bounds__(256) void prep_all(const float* __restrict__ X,
                                                const float* __restrict__ Wq,
                                                const float* __restrict__ Wk,
                                                const float* __restrict__ Wo,
                                                const float* __restrict__ Wv,
                                                unsigned short* __restrict__ Xbf,
                                                unsigned short* __restrict__ XTg,
                                                unsigned short* __restrict__ GT,
                                                unsigned short* __restrict__ W2) {
    __shared__ unsigned Tt[2320];          // 9,280 B
    const int bi = blockIdx.x, tid = threadIdx.x;
    if (bi < 1024) {
        const int st = bi & 31, h = (bi >> 5) & 7, b = bi >> 8;
        const int s0 = st * 64;
        const int j = tid >> 2, g = tid & 3;
        const float* src = X + ((size_t)(b * S_ + s0 + j) * E_) + h * 64 + g * 16;
        unsigned short us[16];
#pragma unroll
        for (int i = 0; i < 16; i += 4) {
            float4 f = *(const float4*)(src + i);
            us[i] = f2bf(f.x); us[i + 1] = f2bf(f.y);
            us[i + 2] = f2bf(f.z); us[i + 3] = f2bf(f.w);
        }
        size_t xb = ((size_t)(b * S_ + s0 + j) * E_) + h * 64 + g * 16;
        *(uint4*)&Xbf[xb]     = *(uint4*)&us[0];
        *(uint4*)&Xbf[xb + 8] = *(uint4*)&us[8];
        // stage as d-pairs: Tt[addr(j, g*8+k)] = (bf16 d=2k', d=2k'+1) of X row j
        {
            const unsigned* p = (const unsigned*)us;   // p[k] = us[2k] | us[2k+1]<<16
            const int base = (j >> 4) * 580 + (j & 15) * 36 + g * 8;
            *(uint4*)&Tt[base]     = *(const uint4*)&p[0];
            *(uint4*)&Tt[base + 4] = *(const uint4*)&p[4];
        }
        __syncthreads();
        // read back transposed+permuted: out[i] = X[s0 + g*16 + pm[i]][d]
        const int d = tid >> 2;
        const int pm[16] = {0,1,2,3,8,9,10,11,4,5,6,7,12,13,14,15};
        const unsigned sel = (d & 1) ? 0x07060302u : 0x05040100u;
        const int rb = g * 580;            // row-group base (rows g*16 + r -> sg = g)
        const int d2 = d >> 1;
        unsigned o32[8];
#pragma unroll
        for (int k = 0; k < 8; ++k) {
            unsigned va = Tt[rb + pm[2 * k]     * 36 + d2];
            unsigned vb = Tt[rb + (pm[2 * k] + 1) * 36 + d2];   // pm pairs are +1-adjacent
            o32[k] = __builtin_amdgcn_perm(vb, va, sel);
        }
        size_t tb = ((size_t)((b * 8 + h) * 64 + d)) * S_ + s0 + g * 16;
        *(uint4*)&XTg[tb]     = *(const uint4*)&o32[0];
        *(uint4*)&XTg[tb + 8] = *(const uint4*)&o32[4];
    } else if (bi < 1040) {
        int idx = (bi - 1024) * 256 + tid;
        int c = idx >> 6, d = idx & 63;
        float acc = 0.f;
#pragma unroll 8
        for (int e = 0; e < 64; ++e) acc += Wq[e * 64 + d] * Wk[e * 64 + c];
        GT[c * 64 + d] = f2bf(acc * 0.18033688011112042f);   // log2(e)/sqrt(64)
    } else {
        int idx = (bi - 1040) * 256 + tid;
        int e = idx >> 9, f = idx & 511;
        int h = f >> 6, c = f & 63;
        const float* wo = Wo + e * 512 + h * 64;
        float acc = 0.f;
#pragma unroll 8
        for (int d = 0; d < 64; ++d) acc += wo[d] * Wv[d * 64 + c];
        W2[idx] = f2bf(acc);
    }
}

// ---------------- MFMA flash attention, K-split=2, double-buffered ----------------
// Round-4 version verbatim (passing, ~50 us): 1024 blocks x 128 threads;
// blk&7 = h -> one head per XCD; 2 waves, 64 q/wave as two 32-q B-groups.
__global__ __launch_bounds__(128, 2) void attn_mfma(const unsigned short* __restrict__ Xbf,
                                                    const unsigned short* __restrict__ XTg,
                                                    const unsigned short* __restrict__ GT,
                                                    unsigned short* __restrict__ AOp,
                                                    float* __restrict__ Lp) {
    __shared__ union SM {
        unsigned short Q[128][72];          // startup Q/U staging (18,432 B)
        unsigned char  cb[2][2][8192];      // [buf][Xrm|XT][64 rows x 128 B] (32,768 B)
        unsigned short AOt[128][72];        // epilogue bounce
    } sm;

    const int tid = threadIdx.x;
    const int w = tid >> 6, lane = tid & 63;
    const int lm = lane & 31, lh = lane >> 5;
    const int h = blockIdx.x & 7;
    const int rest = blockIdx.x >> 3;            // 0..127
    const int qt = rest & 15, b = (rest >> 4) & 3, split = rest >> 6;
    const int s0 = qt * 128, sk0 = split * (S_ / 2);

    // ---- stage 128 Q rows (2 passes of 64 rows with 128 threads)
    {
        const int r = tid >> 1, c = (tid & 1) * 32;
#pragma unroll
        for (int p = 0; p < 2; ++p) {
            const unsigned short* src = Xbf + ((size_t)(b * S_ + s0 + 64 * p + r)) * E_ + h * 64 + c;
#pragma unroll
            for (int u = 0; u < 4; ++u)
                *(uint4*)&sm.Q[64 * p + r][c + u * 8] = *(const uint4*)(src + u * 8);
        }
    }
    __syncthreads();

    // ---- U = Xq @ (G*kScale), 64 queries per wave; LDS round-trip within own
    // wave's rows; keep B-frags for both q-groups in regs (verified math)
    bf16x8 Ufrag[2][4];
    {
        f32x16 ua[2][2];
#pragma unroll
        for (int mt = 0; mt < 2; ++mt)
#pragma unroll
            for (int nt = 0; nt < 2; ++nt)
#pragma unroll
                for (int i = 0; i < 16; ++i) ua[mt][nt][i] = 0.f;
#pragma unroll
        for (int ks = 0; ks < 4; ++ks) {
            bf16x8 bG0 = *(const bf16x8*)&GT[(lm +  0) * 64 + ks * 16 + lh * 8];
            bf16x8 bG1 = *(const bf16x8*)&GT[(lm + 32) * 64 + ks * 16 + lh * 8];
#pragma unroll
            for (int mt = 0; mt < 2; ++mt) {
                bf16x8 aQ = *(const bf16x8*)&sm.Q[64 * w + 32 * mt + lm][ks * 16 + lh * 8];
                ua[mt][0] = __builtin_amdgcn_mfma_f32_32x32x16_bf16(aQ, bG0, ua[mt][0], 0, 0, 0);
                ua[mt][1] = __builtin_amdgcn_mfma_f32_32x32x16_bf16(aQ, bG1, ua[mt][1], 0, 0, 0);
            }
        }
#pragma unroll
        for (int mt = 0; mt < 2; ++mt)
#pragma unroll
            for (int nt = 0; nt < 2; ++nt)
#pragma unroll
                for (int r = 0; r < 16; ++r)
                    sm.Q[64 * w + 32 * mt + (r & 3) + 8 * (r >> 2) + 4 * lh][lm + 32 * nt] =
                        f2bf(ua[mt][nt][r]);
#pragma unroll
        for (int g = 0; g < 2; ++g)
#pragma unroll
            for (int ks = 0; ks < 4; ++ks)
                Ufrag[g][ks] = *(const bf16x8*)&sm.Q[64 * w + 32 * g + lm][ks * 16 + lh * 8];
    }
    __syncthreads();   // all U-phase LDS traffic done before cb staging clobbers union

    // ---- pre-swizzled per-lane global source addresses for gload_lds staging.
    const int il = lane >> 3;                         // sub-row within one 1 KiB instr
    const int swc = ((lane & 7) ^ (il & 7)) * 8;      // swizzled col, ushort units
    const unsigned short* gX0 = Xbf + ((size_t)(b * S_ + sk0 + 32 * w + il)) * E_ + h * 64 + swc;
    const unsigned short* gT0 = XTg + ((size_t)((b * 8 + h) * 64 + 32 * w + il)) * S_ + sk0 + swc;

    // stage chunk 0 into cb[0]
#pragma unroll
    for (int i8 = 0; i8 < 4; ++i8) {
        __builtin_amdgcn_global_load_lds((const unsigned*)(gX0 + (size_t)i8 * 8 * E_),
                                         (unsigned*)&sm.cb[0][0][(4 * w + i8) * 1024], 16, 0, 0);
        __builtin_amdgcn_global_load_lds((const unsigned*)(gT0 + (size_t)i8 * 8 * S_),
                                         (unsigned*)&sm.cb[0][1][(4 * w + i8) * 1024], 16, 0, 0);
    }
    __syncthreads();

    float lsum0 = 0.f, lsum1 = 0.f;
    f32x16 AO[2][2];
#pragma unroll
    for (int mt = 0; mt < 2; ++mt)
#pragma unroll
        for (int nt = 0; nt < 2; ++nt)
#pragma unroll
            for (int i = 0; i < 16; ++i) AO[mt][nt][i] = 0.f;

    // shared const-zero accumulator seed: C operand of every chunk's ks=0 MFMAs
    f32x16 zv;
#pragma unroll
    for (int i = 0; i < 16; ++i) zv[i] = 0.f;

    const int xorr = (lm & 7) << 4;                   // read-side swizzle term

    for (int ck = 0; ck < 16; ++ck) {
        const int rb = ck & 1;
        // issue next-chunk staging FIRST: loads fly across the whole compute phase
        if (ck < 15) {
            const unsigned short* sX = gX0 + (size_t)(ck + 1) * 64 * E_;
            const unsigned short* sT = gT0 + (ck + 1) * 64;
            unsigned char* dX = &sm.cb[rb ^ 1][0][4 * w * 1024];
            unsigned char* dT = &sm.cb[rb ^ 1][1][4 * w * 1024];
#pragma unroll
            for (int i8 = 0; i8 < 4; ++i8) {
                __builtin_amdgcn_global_load_lds((const unsigned*)(sX + (size_t)i8 * 8 * E_),
                                                 (unsigned*)(dX + i8 * 1024), 16, 0, 0);
                __builtin_amdgcn_global_load_lds((const unsigned*)(sT + (size_t)i8 * 8 * S_),
                                                 (unsigned*)(dT + i8 * 1024), 16, 0, 0);
            }
        }

        const unsigned char* bX = sm.cb[rb][0];
        const unsigned char* bT = sm.cb[rb][1];

        // ---- QK: ALL 64 scores as one MFMA cluster; ks=0 seeds from const zv
        f32x16 sc[2][2];
        __builtin_amdgcn_s_setprio(1);
#pragma unroll
        for (int mt = 0; mt < 2; ++mt) {
            bf16x8 aX = *(const bf16x8*)(bX + (32 * mt + lm) * 128 + ((lh * 16) ^ xorr));
            sc[mt][0] = __builtin_amdgcn_mfma_f32_32x32x16_bf16(aX, Ufrag[0][0], zv, 0, 0, 0);
            sc[mt][1] = __builtin_amdgcn_mfma_f32_32x32x16_bf16(aX, Ufrag[1][0], zv, 0, 0, 0);
        }
#pragma unroll
        for (int ks = 1; ks < 4; ++ks)
#pragma unroll
            for (int mt = 0; mt < 2; ++mt) {
                bf16x8 aX = *(const bf16x8*)(bX + (32 * mt + lm) * 128 + ((ks * 32 + lh * 16) ^ xorr));
                sc[mt][0] = __builtin_amdgcn_mfma_f32_32x32x16_bf16(aX, Ufrag[0][ks], sc[mt][0], 0, 0, 0);
                sc[mt][1] = __builtin_amdgcn_mfma_f32_32x32x16_bf16(aX, Ufrag[1][ks], sc[mt][1], 0, 0, 0);
            }
        __builtin_amdgcn_s_setprio(0);

        // ---- exp/PV streamed per-js: exp(js) overlaps QK tail / PV(js-1)
#pragma unroll
        for (int js = 0; js < 4; ++js) {
            const int mt = js >> 1, jh = js & 1;
            union { unsigned u[4]; bf16x8 v; } bP0, bP1;
#pragma unroll
            for (int i = 0; i < 4; ++i) {
                const int qq = 2 * jh + (i >> 1);
                float pa = fexp2(sc[mt][0][qq * 4 + 2 * (i & 1)]);
                float pb = fexp2(sc[mt][0][qq * 4 + 2 * (i & 1) + 1]);
                lsum0 += pa + pb;
                bP0.u[i] = pk2bf(pa, pb);
                float pc = fexp2(sc[mt][1][qq * 4 + 2 * (i & 1)]);
                float pd = fexp2(sc[mt][1][qq * 4 + 2 * (i & 1) + 1]);
                lsum1 += pc + pd;
                bP1.u[i] = pk2bf(pc, pd);
            }
            __builtin_amdgcn_s_setprio(1);
#pragma unroll
            for (int mtv = 0; mtv < 2; ++mtv) {
                bf16x8 aT = *(const bf16x8*)(bT + (32 * mtv + lm) * 128 + ((js * 32 + lh * 16) ^ xorr));
                AO[mtv][0] = __builtin_amdgcn_mfma_f32_32x32x16_bf16(aT, bP0.v, AO[mtv][0], 0, 0, 0);
                AO[mtv][1] = __builtin_amdgcn_mfma_f32_32x32x16_bf16(aT, bP1.v, AO[mtv][1], 0, 0, 0);
            }
            __builtin_amdgcn_s_setprio(0);
        }
        // one barrier per chunk: drains gload_lds (vmcnt) + all LDS reads, then swap
        __syncthreads();
    }

    // ---- epilogue: combine lane halves of lsum; write UNNORMALIZED bf16 partial
    lsum0 += __shfl_xor(lsum0, 32);
    lsum1 += __shfl_xor(lsum1, 32);
#pragma unroll
    for (int mtv = 0; mtv < 2; ++mtv)
#pragma unroll
        for (int nt = 0; nt < 2; ++nt)
#pragma unroll
            for (int qq = 0; qq < 4; ++qq) {
                const int d0 = 32 * mtv + 8 * qq + 4 * lh;
                const int row = 64 * w + 32 * nt + lm;
                *(unsigned*)&sm.AOt[row][d0] =
                    pk2bf(AO[mtv][nt][qq * 4 + 0], AO[mtv][nt][qq * 4 + 1]);
                *(unsigned*)&sm.AOt[row][d0 + 2] =
                    pk2bf(AO[mtv][nt][qq * 4 + 2], AO[mtv][nt][qq * 4 + 3]);
            }
    __syncthreads();
    {
        const int r = tid >> 1, c = (tid & 1) * 32;
#pragma unroll
        for (int p = 0; p < 2; ++p) {
            unsigned short* dst = AOp + (size_t)split * SPLIT_STRIDE
                                + ((size_t)(b * S_ + s0 + 64 * p + r)) * E_ + h * 64 + c;
#pragma unroll
            for (int u = 0; u < 4; ++u)
                *(uint4*)(dst + u * 8) = *(const uint4*)&sm.AOt[64 * p + r][c + u * 8];
        }
    }
    if (lane < 32) {
        const size_t lb = ((size_t)(split * 4 + b) * 8 + h) * S_ + s0 + 64 * w;
        Lp[lb + lm]      = lsum0;
        Lp[lb + 32 + lm] = lsum1;
    }
}

// ---------------- output GEMM with fused split-combine + normalize ----------------
// Round-7: XCD-locality decode. OLD: et=blk&7 -> the 8 et-blocks sharing one
// rt-strip land on 8 DIFFERENT XCDs (round-robin dispatch), so every XCD
// re-fetches the strip from HBM: AOp read traffic 8x33.6 = 134 MB. NEW:
// rt = (blk&7)*16 + ((blk>>3)&15), et = blk>>7  ==>  xcd = blk&7 = rt>>4:
// all 8 et-blocks of a strip share an XCD; per-XCD working set 16 strips x
// 128 KB = 2 MB + W2 0.5 MB fits the 4 MB XCD L2; all 128 blocks/XCD are
// co-resident (4/CU x 32 CU). AOp HBM traffic -> ~34 MB. Bijective relabel,
// per-block work bit-identical.
__global__ __launch_bounds__(256) void out_gemm_bf(const unsigned short* __restrict__ AOp,
                                                   const float* __restrict__ Lp,
                                                   const unsigned short* __restrict__ W2,
                                                   const float* __restrict__ bo,
                                                   float* __restrict__ out) {
    __shared__ unsigned short At[64][72];
    __shared__ unsigned short Bt[64][72];
    const int tid = threadIdx.x;
    const int w = tid >> 6, lane = tid & 63;
    const int lm = lane & 31, lh = lane >> 5;
    const int et = blockIdx.x >> 7;
    const int rt = (blockIdx.x & 7) * 16 + ((blockIdx.x >> 3) & 15);
    const int r0 = rt * 64, e0 = et * 64;
    const int rr = tid >> 2, cc = (tid & 3) * 16;
    const int srow = r0 + rr, bb = srow >> 11, ss = srow & 2047;

    f32x16 acc;
#pragma unroll
    for (int i = 0; i < 16; ++i) acc[i] = 0.f;

    for (int k0 = 0; k0 < 512; k0 += 64) {
        const int hh = k0 >> 6;
        const float linv = 1.0f / (Lp[((size_t)(bb)*8 + hh) * S_ + ss] +
                                   Lp[((size_t)(4 + bb) * 8 + hh) * S_ + ss]);
        __syncthreads();
        {
            const unsigned short* a0 = AOp + (size_t)srow * 512 + k0 + cc;
            const unsigned short* a1 = a0 + SPLIT_STRIDE;
            uint4 u0 = *(const uint4*)a0, u0b = *(const uint4*)(a0 + 8);
            uint4 u1 = *(const uint4*)a1, u1b = *(const uint4*)(a1 + 8);
            uint4 o, ob;
            o.x  = pk2bf((bflo(u0.x) + bflo(u1.x)) * linv, (bfhi(u0.x) + bfhi(u1.x)) * linv);
            o.y  = pk2bf((bflo(u0.y) + bflo(u1.y)) * linv, (bfhi(u0.y) + bfhi(u1.y)) * linv);
            o.z  = pk2bf((bflo(u0.z) + bflo(u1.z)) * linv, (bfhi(u0.z) + bfhi(u1.z)) * linv);
            o.w  = pk2bf((bflo(u0.w) + bflo(u1.w)) * linv, (bfhi(u0.w) + bfhi(u1.w)) * linv);
            ob.x = pk2bf((bflo(u0b.x) + bflo(u1b.x)) * linv, (bfhi(u0b.x) + bfhi(u1b.x)) * linv);
            ob.y = pk2bf((bflo(u0b.y) + bflo(u1b.y)) * linv, (bfhi(u0b.y) + bfhi(u1b.y)) * linv);
            ob.z = pk2bf((bflo(u0b.z) + bflo(u1b.z)) * linv, (bfhi(u0b.z) + bfhi(u1b.z)) * linv);
            ob.w = pk2bf((bflo(u0b.w) + bflo(u1b.w)) * linv, (bfhi(u0b.w) + bfhi(u1b.w)) * linv);
            *(uint4*)&At[rr][cc]     = o;
            *(uint4*)&At[rr][cc + 8] = ob;
            const unsigned short* sb = W2 + (size_t)(e0 + rr) * 512 + k0 + cc;
            *(uint4*)&Bt[rr][cc]     = *(const uint4*)sb;
            *(uint4*)&Bt[rr][cc + 8] = *(const uint4*)(sb + 8);
        }
        __syncthreads();
#pragma unroll
        for (int ks = 0; ks < 4; ++ks) {
            bf16x8 aA = *(const bf16x8*)&At[32 * (w & 1) + lm][ks * 16 + lh * 8];
            bf16x8 bW = *(const bf16x8*)&Bt[32 * (w >> 1) + lm][ks * 16 + lh * 8];
            acc = __builtin_amdgcn_mfma_f32_32x32x16_bf16(aA, bW, acc, 0, 0, 0);
        }
    }
    const float bv = bo[e0 + 32 * (w >> 1) + lm];
#pragma unroll
    for (int r = 0; r < 16; ++r) {
        int orow = r0 + 32 * (w & 1) + (r & 3) + 8 * (r >> 2) + 4 * lh;
        out[(size_t)orow * 512 + e0 + 32 * (w >> 1) + lm] = acc[r] + bv;
    }
}

extern "C" void kernel_launch(void* const* d_in, const int* in_sizes, int n_in,
                              void* d_out, int out_size, void* d_ws, size_t ws_size,
                              hipStream_t stream) {
    (void)in_sizes; (void)n_in; (void)out_size; (void)ws_size;
    const float* X  = (const float*)d_in[0];   // queries (K/V derive from it, per reference)
    const float* Wq = (const float*)d_in[3];
    const float* Wk = (const float*)d_in[4];
    const float* Wv = (const float*)d_in[5];
    const float* Wo = (const float*)d_in[6];
    const float* bo = (const float*)d_in[7];

    float* ws = (float*)d_ws;
    unsigned short* W2bf = (unsigned short*)ws;                        // 262,144 us
    unsigned short* GT   = (unsigned short*)(ws + 131072);             // 4,096 us
    unsigned short* Xbf  = (unsigned short*)(ws + 133120);             // 4,194,304 us
    unsigned short* XTg  = (unsigned short*)(ws + 2230272);            // 4,194,304 us
    unsigned short* AOp  = (unsigned short*)(ws + 4327424);            // 2 x 4,194,304 us
    float*          Lp   = ws + 8521728;                               // 131,072 f (~34.6 MB total)

    prep_all   <<<2064, 256, 0, stream>>>(X, Wq, Wk, Wo, Wv, Xbf, XTg, GT, W2bf);
    attn_mfma  <<<1024, 128, 0, stream>>>(Xbf, XTg, GT, AOp, Lp);
    out_gemm_bf<<<1024, 256, 0, stream>>>(AOp, Lp, W2bf, bo, (float*)d_out);
}